// Round 1
// baseline (339.505 us; speedup 1.0000x reference)
//
#include <hip/hip_runtime.h>

#define NUM_GRAPHS 1024
#define F_DIM 512

// Workspace layout: A[g*8 + j] for j=0..6 = per-graph feature-dot sums,
// A[g*8 + 7] = node count for graph g. Total 1024*8 floats = 32 KB.

__global__ void zero_ws_kernel(float* __restrict__ A, int n) {
    int i = blockIdx.x * blockDim.x + threadIdx.x;
    if (i < n) A[i] = 0.0f;
}

__device__ __forceinline__ void flush_segment(float (&acc)[7], int seg_cnt,
                                              int g, int lane,
                                              float* __restrict__ A) {
    #pragma unroll
    for (int j = 0; j < 7; ++j) {
        float v = acc[j];
        #pragma unroll
        for (int off = 32; off > 0; off >>= 1)
            v += __shfl_down(v, off, 64);
        if (lane == 0) atomicAdd(A + g * 8 + j, v);
    }
    if (lane == 0) atomicAdd(A + g * 8 + 7, (float)seg_cnt);
}

// One wave per contiguous node chunk. Lane l owns features [8l, 8l+8).
// batch ids are sorted, so we accumulate per-lane partials for the current
// graph and only reduce+atomic-flush at segment boundaries.
__global__ __launch_bounds__(256) void node_accum_kernel(
        const float* __restrict__ x, const int* __restrict__ batch,
        const float* __restrict__ W, float* __restrict__ A, int N) {
    const int lane = threadIdx.x & 63;
    const int wave = (blockIdx.x * blockDim.x + threadIdx.x) >> 6;
    const int num_waves = (gridDim.x * blockDim.x) >> 6;
    const int K = (N + num_waves - 1) / num_waves;
    const int start = wave * K;
    const int end = min(start + K, N);
    if (start >= end) return;

    // W fragment in registers: lane holds W[j][8*lane .. 8*lane+8) for j=0..6
    float4 w0[7], w1[7];
    #pragma unroll
    for (int j = 0; j < 7; ++j) {
        const float4* wp = (const float4*)(W + j * F_DIM + lane * 8);
        w0[j] = wp[0];
        w1[j] = wp[1];
    }

    float acc[7];
    #pragma unroll
    for (int j = 0; j < 7; ++j) acc[j] = 0.0f;
    int cur_g = batch[start];   // wave-uniform (broadcast load)
    int seg_cnt = 0;

    for (int i = start; i < end; ++i) {
        int g = batch[i];
        if (g != cur_g) {       // wave-uniform branch
            flush_segment(acc, seg_cnt, cur_g, lane, A);
            cur_g = g;
            seg_cnt = 0;
            #pragma unroll
            for (int j = 0; j < 7; ++j) acc[j] = 0.0f;
        }
        const float4* xp = (const float4*)(x + (size_t)i * F_DIM + lane * 8);
        float4 a = xp[0];
        float4 c = xp[1];
        #pragma unroll
        for (int j = 0; j < 7; ++j) {
            acc[j] += a.x * w0[j].x + a.y * w0[j].y + a.z * w0[j].z + a.w * w0[j].w
                    + c.x * w1[j].x + c.y * w1[j].y + c.z * w1[j].z + c.w * w1[j].w;
        }
        ++seg_cnt;
    }
    flush_segment(acc, seg_cnt, cur_g, lane, A);
}

__global__ void finalize_kernel(const float* __restrict__ A,
                                const float* __restrict__ b,
                                float* __restrict__ out) {
    int idx = blockIdx.x * blockDim.x + threadIdx.x;
    if (idx >= NUM_GRAPHS * 7) return;
    int g = idx / 7;
    int j = idx - g * 7;
    float cnt = A[g * 8 + 7];
    out[idx] = A[g * 8 + j] / fmaxf(cnt, 1.0f) + b[j];
}

extern "C" void kernel_launch(void* const* d_in, const int* in_sizes, int n_in,
                              void* d_out, int out_size, void* d_ws, size_t ws_size,
                              hipStream_t stream) {
    // Input order: x[100000,512] f32, edge_index (UNUSED), edge_attr (UNUSED),
    // batch_size[100000] int, W[7,512] f32, b[7] f32.
    const float* x     = (const float*)d_in[0];
    const int*   batch = (const int*)d_in[3];
    const float* W     = (const float*)d_in[4];
    const float* b     = (const float*)d_in[5];
    float* out = (float*)d_out;
    float* A   = (float*)d_ws;           // 1024*8 floats = 32 KB
    const int N = in_sizes[3];           // 100000 nodes

    const int ws_elems = NUM_GRAPHS * 8;
    zero_ws_kernel<<<(ws_elems + 255) / 256, 256, 0, stream>>>(A, ws_elems);

    // 1024 blocks * 256 thr = 4096 waves, ~25 contiguous nodes per wave.
    node_accum_kernel<<<1024, 256, 0, stream>>>(x, batch, W, A, N);

    finalize_kernel<<<(NUM_GRAPHS * 7 + 255) / 256, 256, 0, stream>>>(A, b, out);
}

// Round 2
// 338.296 us; speedup vs baseline: 1.0036x; 1.0036x over previous
//
#include <hip/hip_runtime.h>

#define NUM_GRAPHS 1024
#define F_DIM 512

// Workspace layout: A[g*8 + j] for j=0..6 = per-graph feature-dot sums,
// A[g*8 + 7] = node count for graph g. Total 1024*8 floats = 32 KB.

__global__ void zero_ws_kernel(float* __restrict__ A, int n) {
    int i = blockIdx.x * blockDim.x + threadIdx.x;
    if (i < n) A[i] = 0.0f;
}

__device__ __forceinline__ void flush_segment(const float (&acc)[7], int seg_cnt,
                                              int g, int lane,
                                              float* __restrict__ A) {
    #pragma unroll
    for (int j = 0; j < 7; ++j) {
        float v = acc[j];
        #pragma unroll
        for (int off = 32; off > 0; off >>= 1)
            v += __shfl_down(v, off, 64);
        if (lane == 0) atomicAdd(A + g * 8 + j, v);
    }
    if (lane == 0) atomicAdd(A + g * 8 + 7, (float)seg_cnt);
}

// One wave per contiguous chunk of K<=64 nodes. Lane l owns features
// [8l, 8l+8). batch ids are sorted; the whole chunk's ids are fetched with a
// single coalesced wave load, segment boundaries found via shfl_up + ballot,
// and each segment runs a branch-free software-pipelined FMA loop.
__global__ __launch_bounds__(256) void node_accum_kernel(
        const float* __restrict__ x, const int* __restrict__ batch,
        const float* __restrict__ W, float* __restrict__ A, int N) {
    const int lane = threadIdx.x & 63;
    const int wave = (blockIdx.x * blockDim.x + threadIdx.x) >> 6;
    const int num_waves = (gridDim.x * blockDim.x) >> 6;
    const int K = (N + num_waves - 1) / num_waves;   // 25 for N=100000, 4096 waves
    const int start = wave * K;
    const int len = min(N - start, K);
    if (len <= 0) return;

    // W fragment in registers: lane holds W[j][8*lane .. 8*lane+8) for j=0..6
    float4 w0[7], w1[7];
    #pragma unroll
    for (int j = 0; j < 7; ++j) {
        const float4* wp = (const float4*)(W + j * F_DIM + lane * 8);
        w0[j] = wp[0];
        w1[j] = wp[1];
    }

    // One coalesced load of the chunk's batch ids (lanes >= len clamp to last).
    int g_l = batch[start + min(lane, len - 1)];
    int g_prev = __shfl_up(g_l, 1, 64);
    unsigned long long bnd =
        __ballot(lane > 0 && lane < len && g_l != g_prev);  // start-of-new-segment lanes

    int s = 0;
    while (s < len) {
        const int g = __shfl(g_l, s, 64);
        // next boundary strictly after s, else len
        unsigned long long m = (s < 63) ? (bnd & (~0ULL << (s + 1))) : 0ULL;
        int e = m ? (__ffsll((long long)m) - 1) : len;

        float acc[7];
        #pragma unroll
        for (int j = 0; j < 7; ++j) acc[j] = 0.0f;

        const int n = e - s;
        const float* xb = x + (size_t)(start + s) * F_DIM + lane * 8;
        // software pipeline: next node's loads in flight during current FMAs
        float4 a = ((const float4*)xb)[0];
        float4 c = ((const float4*)xb)[1];
        for (int t = 1; t < n; ++t) {
            const float* xn = xb + (size_t)t * F_DIM;
            float4 na = ((const float4*)xn)[0];
            float4 nc = ((const float4*)xn)[1];
            #pragma unroll
            for (int j = 0; j < 7; ++j) {
                acc[j] += a.x * w0[j].x + a.y * w0[j].y + a.z * w0[j].z + a.w * w0[j].w
                        + c.x * w1[j].x + c.y * w1[j].y + c.z * w1[j].z + c.w * w1[j].w;
            }
            a = na; c = nc;
        }
        #pragma unroll
        for (int j = 0; j < 7; ++j) {
            acc[j] += a.x * w0[j].x + a.y * w0[j].y + a.z * w0[j].z + a.w * w0[j].w
                    + c.x * w1[j].x + c.y * w1[j].y + c.z * w1[j].z + c.w * w1[j].w;
        }

        flush_segment(acc, n, g, lane, A);
        s = e;
    }
}

__global__ void finalize_kernel(const float* __restrict__ A,
                                const float* __restrict__ b,
                                float* __restrict__ out) {
    int idx = blockIdx.x * blockDim.x + threadIdx.x;
    if (idx >= NUM_GRAPHS * 7) return;
    int g = idx / 7;
    int j = idx - g * 7;
    float cnt = A[g * 8 + 7];
    out[idx] = A[g * 8 + j] / fmaxf(cnt, 1.0f) + b[j];
}

extern "C" void kernel_launch(void* const* d_in, const int* in_sizes, int n_in,
                              void* d_out, int out_size, void* d_ws, size_t ws_size,
                              hipStream_t stream) {
    // Input order: x[100000,512] f32, edge_index (UNUSED), edge_attr (UNUSED),
    // batch_size[100000] int, W[7,512] f32, b[7] f32.
    const float* x     = (const float*)d_in[0];
    const int*   batch = (const int*)d_in[3];
    const float* W     = (const float*)d_in[4];
    const float* b     = (const float*)d_in[5];
    float* out = (float*)d_out;
    float* A   = (float*)d_ws;           // 1024*8 floats = 32 KB
    const int N = in_sizes[3];           // 100000 nodes

    const int ws_elems = NUM_GRAPHS * 8;
    zero_ws_kernel<<<(ws_elems + 255) / 256, 256, 0, stream>>>(A, ws_elems);

    // 1024 blocks * 256 thr = 4096 waves, 25 contiguous nodes per wave (<=64).
    node_accum_kernel<<<1024, 256, 0, stream>>>(x, batch, W, A, N);

    finalize_kernel<<<(NUM_GRAPHS * 7 + 255) / 256, 256, 0, stream>>>(A, b, out);
}